// Round 3
// baseline (649.763 us; speedup 1.0000x reference)
//
#include <hip/hip_runtime.h>
#include <hip/hip_bf16.h>
#include <cstddef>

// ---------------------------------------------------------------------------
// 2-layer GCN: out = A_norm(relu(A_norm(x@W1)+b1) @ W2) + b2
// R8: GEMM2 fused into agg1 (k_agg1mm); k_dinv+k_scan2 merged into k_scan3;
//     dispatches 9 -> 7; h1 global round-trip (51.2 MB) eliminated.
// R9: fp32->bf16 via v_cvt_pk_bf16_f32 (inline asm; no builtin on gfx950).
// R10: k_fused GEMM phase de-LDS'd ("flatmm" shape): A frags loaded straight
//     from global (each A element used by exactly ONE fragment slot -> LDS
//     staging was pure overhead), B frags straight from L2-resident W1T
//     (128 KB, read by all blocks). Zero LDS, ZERO barriers in the K-loop;
//     compiler free-pipelines {10 VMEM + 4 cvt + 8 MFMA} per step.
//     Audit of mapping vs verified staged version:
//       a_frag = bf16(A[rowBase+wave*16+l16][k0 + q*8 .. +7])
//       b_frag[nt] = W1T[(nt*16+l16)*IN_F + k0 + q*8 .. +7]
// ---------------------------------------------------------------------------

#define IN_F 512
#define HID 128
#define NCLS 32

typedef __attribute__((ext_vector_type(8))) short bf16x8;
typedef __attribute__((ext_vector_type(4))) float f32x4;

__device__ __forceinline__ unsigned short f2bf(float f) {
    union { float f; unsigned u; } v; v.f = f;
    unsigned r = v.u + 0x7fff + ((v.u >> 16) & 1);   // RNE
    return (unsigned short)(r >> 16);
}
__device__ __forceinline__ float bf2f(unsigned short h) {
    union { unsigned u; float f; } v; v.u = ((unsigned)h) << 16;
    return v.f;
}
__device__ __forceinline__ float lo16(unsigned u) { return bf2f((unsigned short)(u & 0xffff)); }
__device__ __forceinline__ float hi16(unsigned u) { return bf2f((unsigned short)(u >> 16)); }
// packed RNE convert: lo16(ret)=cvt(a), hi16(ret)=cvt(b)  [gfx950, no builtin]
__device__ __forceinline__ unsigned cvt_pk_bf16(float a, float b) {
    unsigned r;
    asm("v_cvt_pk_bf16_f32 %0, %1, %2" : "=v"(r) : "v"(a), "v"(b));
    return r;
}
// 8 fp32 -> bf16x8 fragment (4 cvt_pk instructions)
__device__ __forceinline__ bf16x8 pk8(float4 lo, float4 hi) {
    union { uint4 u; bf16x8 v; } r;
    r.u.x = cvt_pk_bf16(lo.x, lo.y);
    r.u.y = cvt_pk_bf16(lo.z, lo.w);
    r.u.z = cvt_pk_bf16(hi.x, hi.y);
    r.u.w = cvt_pk_bf16(hi.z, hi.w);
    return r.v;
}

// ---------------- hist (stores per-edge rank) fused with W1/W2 transpose/cast ----------------
__global__ void k_histprep(const int* __restrict__ dst, int* __restrict__ deg,
                           int* __restrict__ rank, int E,
                           const float* __restrict__ W1, unsigned short* __restrict__ W1T,
                           const float* __restrict__ W2, unsigned short* __restrict__ W2T, int PB) {
    int b = blockIdx.x;
    if (b < PB) {   // prep: W1T (65536) + W2T (4096) elements
        int i = b * 256 + threadIdx.x;
        if (i < HID * IN_F) {
            int n = i >> 9, k = i & 511;
            W1T[(size_t)n * IN_F + k] = f2bf(W1[(size_t)k * HID + n]);
        } else {
            int j = i - HID * IN_F;
            int c = j >> 7, k = j & 127;           // W2T[c][k] = W2[k][c]
            W2T[(size_t)c * HID + k] = f2bf(W2[(size_t)k * NCLS + c]);
        }
    } else {
        int e = (b - PB) * 256 + threadIdx.x;
        if (e < E) rank[e] = atomicAdd(&deg[dst[e]], 1);
    }
}

// ---------------- 2-level exclusive scan over PADDED counts ((deg+7)&~7) ----------------
__global__ __launch_bounds__(256) void k_scan1(const int* __restrict__ deg, int* __restrict__ rs,
                                               int* __restrict__ bsum, int n) {
    __shared__ int sd[256];
    int base = blockIdx.x * 2048 + threadIdx.x * 8;
    int v[8];
    int t = 0;
#pragma unroll
    for (int i = 0; i < 8; ++i) {
        int x = (base + i < n) ? ((deg[base + i] + 7) & ~7) : 0;
        v[i] = t;
        t += x;
    }
    sd[threadIdx.x] = t;
    __syncthreads();
    for (int off = 1; off < 256; off <<= 1) {
        int x = 0;
        if ((int)threadIdx.x >= off) x = sd[threadIdx.x - off];
        __syncthreads();
        if ((int)threadIdx.x >= off) sd[threadIdx.x] += x;
        __syncthreads();
    }
    int texcl = sd[threadIdx.x] - t;
#pragma unroll
    for (int i = 0; i < 8; ++i)
        if (base + i < n) rs[base + i] = texcl + v[i];
    if (threadIdx.x == 255) bsum[blockIdx.x] = sd[255];
}

// finalize rs (per-block scan of bsum), fill pad slots of csr with dummy index n,
// compute dinv, zero dummy hs/h2s rows.
__global__ __launch_bounds__(256) void k_scan3(int* __restrict__ rs, const int* __restrict__ bsum,
                                               const int* __restrict__ deg, int* __restrict__ csr,
                                               float* __restrict__ dinv,
                                               unsigned* __restrict__ hsu, unsigned* __restrict__ h2su,
                                               int n, int nb) {
    __shared__ int sb[256];
    __shared__ int se[256];
    int t = threadIdx.x;
    int val = (t < nb) ? bsum[t] : 0;
    sb[t] = val;
    __syncthreads();
    for (int off = 1; off < 256; off <<= 1) {
        int x = 0;
        if (t >= off) x = sb[t - off];
        __syncthreads();
        sb[t] += x;
        __syncthreads();
    }
    se[t] = sb[t] - val;        // exclusive block prefix
    __syncthreads();
    int i = blockIdx.x * 256 + t;
    if (i < n) {
        int d = deg[i];
        dinv[i] = rsqrtf((float)d + 1.0f);
        int r = rs[i] + se[i >> 11];
        rs[i] = r;
        int pc = (d + 7) & ~7;
        for (int j = d; j < pc; ++j) csr[r + j] = n;
    }
    if (blockIdx.x == 0) {
        if (t < 64) hsu[(size_t)n * 64 + t] = 0u;   // hs row N = 0
        if (t < 16) h2su[(size_t)n * 16 + t] = 0u;  // h2s row N = 0
    }
}

// ---------------- FUSED: barrier-free GEMM1 (even blocks) + scatter (odd blocks) ----------
#define SCHUNK 1024
__global__ __launch_bounds__(256) void k_fused(const float* __restrict__ A,
                                               const unsigned short* __restrict__ BT,
                                               const float* __restrict__ dinv,
                                               unsigned short* __restrict__ C, int M,
                                               const int* __restrict__ src, const int* __restrict__ dst,
                                               const int* __restrict__ rank, const int* __restrict__ rs,
                                               int* __restrict__ csr, int E) {
    const int bid = blockIdx.x;
    const int tid = threadIdx.x;
    if (bid & 1) {
        // ---- scatter: csr[rs[dst]+rank] = src, no atomics, 4 chains in flight ----
        int base = (bid >> 1) * SCHUNK + tid;
        int d[4], s[4], rk[4];
        bool val[4];
#pragma unroll
        for (int j = 0; j < 4; ++j) {
            int e = base + j * 256;
            val[j] = e < E;
            if (val[j]) { d[j] = dst[e]; s[j] = src[e]; rk[j] = rank[e]; }
        }
#pragma unroll
        for (int j = 0; j < 4; ++j)
            if (val[j]) csr[rs[d[j]] + rk[j]] = s[j];
        return;
    }
    // ---- GEMM phase: no LDS, no barriers ----
    const int wave = tid >> 6;
    const int lane = tid & 63;
    const int l16 = lane & 15;
    const int q = lane >> 4;
    const int rowBase = (bid >> 1) * 64;
    const int arow = rowBase + wave * 16 + l16;      // the one A row this lane feeds
    const bool aval = arow < M;
    const float* aptr = A + (size_t)arow * IN_F + q * 8;          // + k0 per step
    const unsigned short* bptr = BT + (size_t)l16 * IN_F + q * 8; // + nt*16*IN_F + k0

    f32x4 acc[8];
#pragma unroll
    for (int nt = 0; nt < 8; ++nt) acc[nt] = (f32x4){0.f, 0.f, 0.f, 0.f};

    float4 a0, a1;
    bf16x8 bfr[8];
    auto ld = [&](int k0, float4& x0, float4& x1, bf16x8* bv) {
        if (aval) {
            x0 = *(const float4*)(aptr + k0);
            x1 = *(const float4*)(aptr + k0 + 4);
        } else {
            x0 = make_float4(0.f, 0.f, 0.f, 0.f);
            x1 = x0;
        }
#pragma unroll
        for (int nt = 0; nt < 8; ++nt)
            bv[nt] = *(const bf16x8*)(bptr + (size_t)nt * 16 * IN_F + k0);
    };

    ld(0, a0, a1, bfr);
    for (int t = 0; t < 16; ++t) {
        float4 na0, na1;
        bf16x8 nb[8];
        if (t < 15) ld((t + 1) * 32, na0, na1, nb);
        bf16x8 a_frag = pk8(a0, a1);
#pragma unroll
        for (int nt = 0; nt < 8; ++nt)
            acc[nt] = __builtin_amdgcn_mfma_f32_16x16x32_bf16(a_frag, bfr[nt], acc[nt], 0, 0, 0);
        a0 = na0; a1 = na1;
#pragma unroll
        for (int nt = 0; nt < 8; ++nt) bfr[nt] = nb[nt];
    }

#pragma unroll
    for (int r = 0; r < 4; ++r) {
        int row = rowBase + wave * 16 + q * 4 + r;
        if (row < M) {
            float sc = dinv[row];
#pragma unroll
            for (int nt = 0; nt < 8; ++nt)
                C[(size_t)row * HID + nt * 16 + l16] = f2bf(acc[nt][r] * sc);
        }
    }
}

// ---------------- agg1 + GEMM2 fused: block = 16 nodes; gather -> LDS h1 tile ->
// waves 0/1 do (16x128)@(128x32) via 4 MFMAs each -> h2s (dinv-scaled) -----------
__global__ __launch_bounds__(256) void k_agg1mm(const unsigned short* __restrict__ hs,
                                                const int* __restrict__ csr,
                                                const int* __restrict__ rs, const int* __restrict__ cnt,
                                                const float* __restrict__ dinv, const float* __restrict__ b1,
                                                const unsigned short* __restrict__ W2T,
                                                unsigned short* __restrict__ h2s, int N) {
    __shared__ unsigned h1s[16 * 68];   // 16 rows x 136 bf16 (stride 136 -> bank-clean)
    const int tid = threadIdx.x;
    const int wave = tid >> 6;
    const int lane = tid & 63;
    const int base = blockIdx.x * 16;
    const unsigned* hrow = (const unsigned*)hs;
    float2 bb = ((const float2*)b1)[lane];
#pragma unroll
    for (int r = 0; r < 4; ++r) {
        int slot = wave * 4 + r;
        int v = base + slot;
        float ox = 0.f, oy = 0.f;
        if (v < N) {
            float dv = dinv[v];
            unsigned u = hrow[(size_t)v * 64 + lane];   // self (pre-scaled)
            float ax = lo16(u), ay = hi16(u);
            int start = rs[v];
            int pc = (cnt[v] + 7) & ~7;
            for (int i = 0; i < pc; i += 8) {
                int s[8];
                unsigned uu[8];
#pragma unroll
                for (int j = 0; j < 8; ++j) s[j] = csr[start + i + j];
#pragma unroll
                for (int j = 0; j < 8; ++j) uu[j] = hrow[(size_t)s[j] * 64 + lane];
#pragma unroll
                for (int j = 0; j < 8; ++j) { ax += lo16(uu[j]); ay += hi16(uu[j]); }
            }
            ox = fmaxf(dv * ax + bb.x, 0.f);
            oy = fmaxf(dv * ay + bb.y, 0.f);
        }
        h1s[slot * 68 + lane] = cvt_pk_bf16(ox, oy);
    }
    __syncthreads();
    if (wave < 2) {     // wave w handles output cols [w*16, w*16+16)
        const int l16 = lane & 15;
        const int q = lane >> 4;
        f32x4 acc = (f32x4){0.f, 0.f, 0.f, 0.f};
        const unsigned short* h1b = (const unsigned short*)h1s;
#pragma unroll
        for (int ks = 0; ks < 4; ++ks) {
            bf16x8 af = *(const bf16x8*)(h1b + l16 * 136 + ks * 32 + q * 8);
            bf16x8 bf_ = *(const bf16x8*)(W2T + (size_t)(wave * 16 + l16) * HID + ks * 32 + q * 8);
            acc = __builtin_amdgcn_mfma_f32_16x16x32_bf16(af, bf_, acc, 0, 0, 0);
        }
#pragma unroll
        for (int r = 0; r < 4; ++r) {
            int v = base + q * 4 + r;
            if (v < N)
                h2s[(size_t)v * NCLS + wave * 16 + l16] = f2bf(acc[r] * dinv[v]);
        }
    }
}

// ---------------- agg2: 16 lanes per node (row = 1 cache line), branchless padded x8 ----------------
__global__ __launch_bounds__(256) void k_agg2(const unsigned short* __restrict__ h2s,
                                              const int* __restrict__ csr,
                                              const int* __restrict__ rs, const int* __restrict__ cnt,
                                              const float* __restrict__ dinv, const float* __restrict__ b2,
                                              float* __restrict__ out, int N) {
    int g = threadIdx.x >> 4;       // node slot 0..15
    int l = threadIdx.x & 15;       // 2 feats per lane
    int v = blockIdx.x * 16 + g;
    if (v >= N) return;
    float dv = dinv[v];
    const unsigned* rows = (const unsigned*)h2s;   // 16 uints per row
    unsigned u = rows[(size_t)v * 16 + l];         // self (pre-scaled)
    float ax = lo16(u), ay = hi16(u);
    int start = rs[v];
    int pc = (cnt[v] + 7) & ~7;
    for (int i = 0; i < pc; i += 8) {
        int s[8];
        unsigned uu[8];
#pragma unroll
        for (int j = 0; j < 8; ++j) s[j] = csr[start + i + j];
#pragma unroll
        for (int j = 0; j < 8; ++j) uu[j] = rows[(size_t)s[j] * 16 + l];
#pragma unroll
        for (int j = 0; j < 8; ++j) { ax += lo16(uu[j]); ay += hi16(uu[j]); }
    }
    float2 bb = ((const float2*)b2)[l];
    float2 o;
    o.x = dv * ax + bb.x;
    o.y = dv * ay + bb.y;
    *((float2*)(out + (size_t)v * NCLS) + l) = o;
}

// ---------------------------------------------------------------------------
extern "C" void kernel_launch(void* const* d_in, const int* in_sizes, int n_in,
                              void* d_out, int out_size, void* d_ws, size_t ws_size,
                              hipStream_t stream) {
    const float* x = (const float*)d_in[0];
    const int* edge_index = (const int*)d_in[1];
    const float* W1 = (const float*)d_in[2];
    const float* b1 = (const float*)d_in[3];
    const float* W2 = (const float*)d_in[4];
    const float* b2 = (const float*)d_in[5];
    float* out = (float*)d_out;

    const int N = in_sizes[0] / IN_F;       // 100000
    const int E = in_sizes[1] / 2;          // 1600000
    const int* e_src = edge_index;
    const int* e_dst = edge_index + E;

    char* ws = (char*)d_ws;
    size_t off = 0;
    auto alloc = [&](size_t bytes) -> char* {
        char* p = ws + off;
        off += (bytes + 255) & ~(size_t)255;
        return p;
    };
    int* deg             = (int*)alloc((size_t)N * 4);
    float* dinv          = (float*)alloc((size_t)N * 4);
    int* rs              = (int*)alloc((size_t)N * 4);
    int* bsum            = (int*)alloc(1024 * 4);
    int* csr             = (int*)alloc(((size_t)E + 8 * (size_t)N) * 4);  // padded CSR
    unsigned short* W1T  = (unsigned short*)alloc((size_t)HID * IN_F * 2);
    unsigned short* W2T  = (unsigned short*)alloc((size_t)NCLS * HID * 2);
    unsigned short* hs   = (unsigned short*)alloc((size_t)(N + 1) * HID * 2);  // +1 dummy zero row
    unsigned short* h2s  = (unsigned short*)alloc((size_t)(N + 1) * NCLS * 2); // +1 dummy zero row
    int* rank            = (int*)alloc((size_t)E * 4);

    const int nbE = (E + 255) / 256;
    const int nbN = (N + 255) / 256;
    const int nbScan = (N + 2047) / 2048;
    const int PB = (HID * IN_F + NCLS * HID) / 256;   // 272 prep blocks (W1T + W2T)
    const int NBG = (N + 63) / 64;                    // gemm tiles; scatter chunks = same count

    hipMemsetAsync(deg, 0, (size_t)N * 4, stream);
    k_histprep<<<PB + nbE, 256, 0, stream>>>(e_dst, deg, rank, E, W1, W1T, W2, W2T, PB);
    k_scan1<<<nbScan, 256, 0, stream>>>(deg, rs, bsum, N);
    k_scan3<<<nbN, 256, 0, stream>>>(rs, bsum, deg, csr, dinv, (unsigned*)hs, (unsigned*)h2s, N, nbScan);

    k_fused<<<2 * NBG, 256, 0, stream>>>(x, W1T, dinv, hs, N, e_src, e_dst, rank, rs, csr, E);

    k_agg1mm<<<(N + 15) / 16, 256, 0, stream>>>(hs, csr, rs, deg, dinv, b1, W2T, h2s, N);
    k_agg2<<<(N + 15) / 16, 256, 0, stream>>>(h2s, csr, rs, deg, dinv, b2, out, N);
}

// Round 5
// 529.048 us; speedup vs baseline: 1.2282x; 1.2282x over previous
//
#include <hip/hip_runtime.h>
#include <hip/hip_bf16.h>
#include <cstddef>

// ---------------------------------------------------------------------------
// 2-layer GCN: out = A_norm(relu(A_norm(x@W1)+b1) @ W2) + b2
// R8: GEMM2 fused into agg1 (k_agg1mm); scans merged; 7 dispatches.
// R9: fp32->bf16 via v_cvt_pk_bf16_f32 (inline asm; no builtin on gfx950).
// R10 (REGRESSED, reverted): fully barrier-free flatmm GEMM1 -> 280us,
//     MfmaUtil 1.8%, VALUBusy 5.6%: compiler serialized the 10 L2
//     loads/K-step into 64 VGPRs (no double-buffer) -> pure latency chain.
//     LESSON: 8 B-fragments/step straight from L2 cannot be register-
//     pipelined; B needs LDS staging (bulk coalesced load + ds_read).
// R11: hybrid: B staged in LDS (byte-identical mapping to the 550us-verified
//     kernel, LSTR=40 pad), A loaded DIRECT from global per-lane (mapping
//     harness-verified in R10 run; A has no cross-lane reuse so its LDS
//     round-trip was pure overhead). LDS = Bs only (10 KB), 8 ds_read/lane.
// R12: identical resubmission of R11 (previous round hit GPUAcquisitionTimeout;
//     no measurement happened). No stacked changes: R10 showed structural GEMM
//     edits can regress 2x, so R11 gets its own clean measurement first.
// ---------------------------------------------------------------------------

#define IN_F 512
#define HID 128
#define NCLS 32

typedef __attribute__((ext_vector_type(8))) short bf16x8;
typedef __attribute__((ext_vector_type(4))) float f32x4;

__device__ __forceinline__ unsigned short f2bf(float f) {
    union { float f; unsigned u; } v; v.f = f;
    unsigned r = v.u + 0x7fff + ((v.u >> 16) & 1);   // RNE
    return (unsigned short)(r >> 16);
}
__device__ __forceinline__ float bf2f(unsigned short h) {
    union { unsigned u; float f; } v; v.u = ((unsigned)h) << 16;
    return v.f;
}
__device__ __forceinline__ float lo16(unsigned u) { return bf2f((unsigned short)(u & 0xffff)); }
__device__ __forceinline__ float hi16(unsigned u) { return bf2f((unsigned short)(u >> 16)); }
// packed RNE convert: lo16(ret)=cvt(a), hi16(ret)=cvt(b)  [gfx950, no builtin]
__device__ __forceinline__ unsigned cvt_pk_bf16(float a, float b) {
    unsigned r;
    asm("v_cvt_pk_bf16_f32 %0, %1, %2" : "=v"(r) : "v"(a), "v"(b));
    return r;
}
// 8 fp32 -> bf16x8 fragment (4 cvt_pk instructions)
__device__ __forceinline__ bf16x8 pk8(float4 lo, float4 hi) {
    union { uint4 u; bf16x8 v; } r;
    r.u.x = cvt_pk_bf16(lo.x, lo.y);
    r.u.y = cvt_pk_bf16(lo.z, lo.w);
    r.u.z = cvt_pk_bf16(hi.x, hi.y);
    r.u.w = cvt_pk_bf16(hi.z, hi.w);
    return r.v;
}

// ---------------- hist (stores per-edge rank) fused with W1/W2 transpose/cast ----------------
__global__ void k_histprep(const int* __restrict__ dst, int* __restrict__ deg,
                           int* __restrict__ rank, int E,
                           const float* __restrict__ W1, unsigned short* __restrict__ W1T,
                           const float* __restrict__ W2, unsigned short* __restrict__ W2T, int PB) {
    int b = blockIdx.x;
    if (b < PB) {   // prep: W1T (65536) + W2T (4096) elements
        int i = b * 256 + threadIdx.x;
        if (i < HID * IN_F) {
            int n = i >> 9, k = i & 511;
            W1T[(size_t)n * IN_F + k] = f2bf(W1[(size_t)k * HID + n]);
        } else {
            int j = i - HID * IN_F;
            int c = j >> 7, k = j & 127;           // W2T[c][k] = W2[k][c]
            W2T[(size_t)c * HID + k] = f2bf(W2[(size_t)k * NCLS + c]);
        }
    } else {
        int e = (b - PB) * 256 + threadIdx.x;
        if (e < E) rank[e] = atomicAdd(&deg[dst[e]], 1);
    }
}

// ---------------- 2-level exclusive scan over PADDED counts ((deg+7)&~7) ----------------
__global__ __launch_bounds__(256) void k_scan1(const int* __restrict__ deg, int* __restrict__ rs,
                                               int* __restrict__ bsum, int n) {
    __shared__ int sd[256];
    int base = blockIdx.x * 2048 + threadIdx.x * 8;
    int v[8];
    int t = 0;
#pragma unroll
    for (int i = 0; i < 8; ++i) {
        int x = (base + i < n) ? ((deg[base + i] + 7) & ~7) : 0;
        v[i] = t;
        t += x;
    }
    sd[threadIdx.x] = t;
    __syncthreads();
    for (int off = 1; off < 256; off <<= 1) {
        int x = 0;
        if ((int)threadIdx.x >= off) x = sd[threadIdx.x - off];
        __syncthreads();
        if ((int)threadIdx.x >= off) sd[threadIdx.x] += x;
        __syncthreads();
    }
    int texcl = sd[threadIdx.x] - t;
#pragma unroll
    for (int i = 0; i < 8; ++i)
        if (base + i < n) rs[base + i] = texcl + v[i];
    if (threadIdx.x == 255) bsum[blockIdx.x] = sd[255];
}

// finalize rs (per-block scan of bsum), fill pad slots of csr with dummy index n,
// compute dinv, zero dummy hs/h2s rows.
__global__ __launch_bounds__(256) void k_scan3(int* __restrict__ rs, const int* __restrict__ bsum,
                                               const int* __restrict__ deg, int* __restrict__ csr,
                                               float* __restrict__ dinv,
                                               unsigned* __restrict__ hsu, unsigned* __restrict__ h2su,
                                               int n, int nb) {
    __shared__ int sb[256];
    __shared__ int se[256];
    int t = threadIdx.x;
    int val = (t < nb) ? bsum[t] : 0;
    sb[t] = val;
    __syncthreads();
    for (int off = 1; off < 256; off <<= 1) {
        int x = 0;
        if (t >= off) x = sb[t - off];
        __syncthreads();
        sb[t] += x;
        __syncthreads();
    }
    se[t] = sb[t] - val;        // exclusive block prefix
    __syncthreads();
    int i = blockIdx.x * 256 + t;
    if (i < n) {
        int d = deg[i];
        dinv[i] = rsqrtf((float)d + 1.0f);
        int r = rs[i] + se[i >> 11];
        rs[i] = r;
        int pc = (d + 7) & ~7;
        for (int j = d; j < pc; ++j) csr[r + j] = n;
    }
    if (blockIdx.x == 0) {
        if (t < 64) hsu[(size_t)n * 64 + t] = 0u;   // hs row N = 0
        if (t < 16) h2su[(size_t)n * 16 + t] = 0u;  // h2s row N = 0
    }
}

// ---------------- FUSED: GEMM1 (B LDS-staged, A direct) + scatter (odd blocks) ----------
#define LSTR 40
#define SCHUNK 1024
__global__ __launch_bounds__(256) void k_fused(const float* __restrict__ A,
                                               const unsigned short* __restrict__ BT,
                                               const float* __restrict__ dinv,
                                               unsigned short* __restrict__ C, int M,
                                               const int* __restrict__ src, const int* __restrict__ dst,
                                               const int* __restrict__ rank, const int* __restrict__ rs,
                                               int* __restrict__ csr, int E) {
    const int bid = blockIdx.x;
    const int tid = threadIdx.x;
    if (bid & 1) {
        // ---- scatter: csr[rs[dst]+rank] = src, no atomics, 4 chains in flight ----
        int base = (bid >> 1) * SCHUNK + tid;
        int d[4], s[4], rk[4];
        bool val[4];
#pragma unroll
        for (int j = 0; j < 4; ++j) {
            int e = base + j * 256;
            val[j] = e < E;
            if (val[j]) { d[j] = dst[e]; s[j] = src[e]; rk[j] = rank[e]; }
        }
#pragma unroll
        for (int j = 0; j < 4; ++j)
            if (val[j]) csr[rs[d[j]] + rk[j]] = s[j];
        return;
    }
    // ---- GEMM phase: B staged in LDS (verified mapping), A direct from global ----
    __shared__ unsigned short Bs[128 * LSTR];
    const int wave = tid >> 6;
    const int lane = tid & 63;
    const int l16 = lane & 15;
    const int q = lane >> 4;
    const int rowBase = (bid >> 1) * 64;

    // A-direct: this lane feeds row (rowBase + wave*16 + l16), cols q*8.. (verified R10)
    const int arow = rowBase + wave * 16 + l16;
    const bool aval = arow < M;
    const float* aptr = A + (size_t)arow * IN_F + q * 8;

    // B staging mapping (verified R7/550us kernel)
    const int bn0 = tid >> 2, bn1 = 64 + (tid >> 2), bkc = tid & 3;

    f32x4 acc[8];
#pragma unroll
    for (int nt = 0; nt < 8; ++nt) acc[nt] = (f32x4){0.f, 0.f, 0.f, 0.f};

    float4 a0, a1;
    uint4 pb0, pb1;
    auto ld = [&](int k0, float4& x0, float4& x1, uint4& b0, uint4& b1) {
        if (aval) {
            x0 = *(const float4*)(aptr + k0);
            x1 = *(const float4*)(aptr + k0 + 4);
        } else {
            x0 = make_float4(0.f, 0.f, 0.f, 0.f);
            x1 = x0;
        }
        b0 = *(const uint4*)(BT + (size_t)bn0 * IN_F + k0 + bkc * 8);
        b1 = *(const uint4*)(BT + (size_t)bn1 * IN_F + k0 + bkc * 8);
    };

    ld(0, a0, a1, pb0, pb1);

    for (int t = 0; t < 16; ++t) {
        *(uint4*)(Bs + bn0 * LSTR + bkc * 8) = pb0;
        *(uint4*)(Bs + bn1 * LSTR + bkc * 8) = pb1;
        __syncthreads();

        float4 na0, na1;
        uint4 nb0, nb1;
        if (t < 15) ld((t + 1) * 32, na0, na1, nb0, nb1);

        bf16x8 a_frag = pk8(a0, a1);
        bf16x8 b_frag[8];
#pragma unroll
        for (int nt = 0; nt < 8; ++nt)
            b_frag[nt] = *(const bf16x8*)(Bs + (nt * 16 + l16) * LSTR + q * 8);
#pragma unroll
        for (int nt = 0; nt < 8; ++nt)
            acc[nt] = __builtin_amdgcn_mfma_f32_16x16x32_bf16(a_frag, b_frag[nt], acc[nt], 0, 0, 0);
        __syncthreads();
        a0 = na0; a1 = na1; pb0 = nb0; pb1 = nb1;
    }

#pragma unroll
    for (int r = 0; r < 4; ++r) {
        int row = rowBase + wave * 16 + q * 4 + r;
        if (row < M) {
            float sc = dinv[row];
#pragma unroll
            for (int nt = 0; nt < 8; ++nt)
                C[(size_t)row * HID + nt * 16 + l16] = f2bf(acc[nt][r] * sc);
        }
    }
}

// ---------------- agg1 + GEMM2 fused: block = 16 nodes; gather -> LDS h1 tile ->
// waves 0/1 do (16x128)@(128x32) via 4 MFMAs each -> h2s (dinv-scaled) -----------
__global__ __launch_bounds__(256) void k_agg1mm(const unsigned short* __restrict__ hs,
                                                const int* __restrict__ csr,
                                                const int* __restrict__ rs, const int* __restrict__ cnt,
                                                const float* __restrict__ dinv, const float* __restrict__ b1,
                                                const unsigned short* __restrict__ W2T,
                                                unsigned short* __restrict__ h2s, int N) {
    __shared__ unsigned h1s[16 * 68];   // 16 rows x 136 bf16 (stride 136 -> bank-clean)
    const int tid = threadIdx.x;
    const int wave = tid >> 6;
    const int lane = tid & 63;
    const int base = blockIdx.x * 16;
    const unsigned* hrow = (const unsigned*)hs;
    float2 bb = ((const float2*)b1)[lane];
#pragma unroll
    for (int r = 0; r < 4; ++r) {
        int slot = wave * 4 + r;
        int v = base + slot;
        float ox = 0.f, oy = 0.f;
        if (v < N) {
            float dv = dinv[v];
            unsigned u = hrow[(size_t)v * 64 + lane];   // self (pre-scaled)
            float ax = lo16(u), ay = hi16(u);
            int start = rs[v];
            int pc = (cnt[v] + 7) & ~7;
            for (int i = 0; i < pc; i += 8) {
                int s[8];
                unsigned uu[8];
#pragma unroll
                for (int j = 0; j < 8; ++j) s[j] = csr[start + i + j];
#pragma unroll
                for (int j = 0; j < 8; ++j) uu[j] = hrow[(size_t)s[j] * 64 + lane];
#pragma unroll
                for (int j = 0; j < 8; ++j) { ax += lo16(uu[j]); ay += hi16(uu[j]); }
            }
            ox = fmaxf(dv * ax + bb.x, 0.f);
            oy = fmaxf(dv * ay + bb.y, 0.f);
        }
        h1s[slot * 68 + lane] = cvt_pk_bf16(ox, oy);
    }
    __syncthreads();
    if (wave < 2) {     // wave w handles output cols [w*16, w*16+16)
        const int l16 = lane & 15;
        const int q = lane >> 4;
        f32x4 acc = (f32x4){0.f, 0.f, 0.f, 0.f};
        const unsigned short* h1b = (const unsigned short*)h1s;
#pragma unroll
        for (int ks = 0; ks < 4; ++ks) {
            bf16x8 af = *(const bf16x8*)(h1b + l16 * 136 + ks * 32 + q * 8);
            bf16x8 bf_ = *(const bf16x8*)(W2T + (size_t)(wave * 16 + l16) * HID + ks * 32 + q * 8);
            acc = __builtin_amdgcn_mfma_f32_16x16x32_bf16(af, bf_, acc, 0, 0, 0);
        }
#pragma unroll
        for (int r = 0; r < 4; ++r) {
            int v = base + q * 4 + r;
            if (v < N)
                h2s[(size_t)v * NCLS + wave * 16 + l16] = f2bf(acc[r] * dinv[v]);
        }
    }
}

// ---------------- agg2: 16 lanes per node (row = 1 cache line), branchless padded x8 ----------------
__global__ __launch_bounds__(256) void k_agg2(const unsigned short* __restrict__ h2s,
                                              const int* __restrict__ csr,
                                              const int* __restrict__ rs, const int* __restrict__ cnt,
                                              const float* __restrict__ dinv, const float* __restrict__ b2,
                                              float* __restrict__ out, int N) {
    int g = threadIdx.x >> 4;       // node slot 0..15
    int l = threadIdx.x & 15;       // 2 feats per lane
    int v = blockIdx.x * 16 + g;
    if (v >= N) return;
    float dv = dinv[v];
    const unsigned* rows = (const unsigned*)h2s;   // 16 uints per row
    unsigned u = rows[(size_t)v * 16 + l];         // self (pre-scaled)
    float ax = lo16(u), ay = hi16(u);
    int start = rs[v];
    int pc = (cnt[v] + 7) & ~7;
    for (int i = 0; i < pc; i += 8) {
        int s[8];
        unsigned uu[8];
#pragma unroll
        for (int j = 0; j < 8; ++j) s[j] = csr[start + i + j];
#pragma unroll
        for (int j = 0; j < 8; ++j) uu[j] = rows[(size_t)s[j] * 16 + l];
#pragma unroll
        for (int j = 0; j < 8; ++j) { ax += lo16(uu[j]); ay += hi16(uu[j]); }
    }
    float2 bb = ((const float2*)b2)[l];
    float2 o;
    o.x = dv * ax + bb.x;
    o.y = dv * ay + bb.y;
    *((float2*)(out + (size_t)v * NCLS) + l) = o;
}

// ---------------------------------------------------------------------------
extern "C" void kernel_launch(void* const* d_in, const int* in_sizes, int n_in,
                              void* d_out, int out_size, void* d_ws, size_t ws_size,
                              hipStream_t stream) {
    const float* x = (const float*)d_in[0];
    const int* edge_index = (const int*)d_in[1];
    const float* W1 = (const float*)d_in[2];
    const float* b1 = (const float*)d_in[3];
    const float* W2 = (const float*)d_in[4];
    const float* b2 = (const float*)d_in[5];
    float* out = (float*)d_out;

    const int N = in_sizes[0] / IN_F;       // 100000
    const int E = in_sizes[1] / 2;          // 1600000
    const int* e_src = edge_index;
    const int* e_dst = edge_index + E;

    char* ws = (char*)d_ws;
    size_t off = 0;
    auto alloc = [&](size_t bytes) -> char* {
        char* p = ws + off;
        off += (bytes + 255) & ~(size_t)255;
        return p;
    };
    int* deg             = (int*)alloc((size_t)N * 4);
    float* dinv          = (float*)alloc((size_t)N * 4);
    int* rs              = (int*)alloc((size_t)N * 4);
    int* bsum            = (int*)alloc(1024 * 4);
    int* csr             = (int*)alloc(((size_t)E + 8 * (size_t)N) * 4);  // padded CSR
    unsigned short* W1T  = (unsigned short*)alloc((size_t)HID * IN_F * 2);
    unsigned short* W2T  = (unsigned short*)alloc((size_t)NCLS * HID * 2);
    unsigned short* hs   = (unsigned short*)alloc((size_t)(N + 1) * HID * 2);  // +1 dummy zero row
    unsigned short* h2s  = (unsigned short*)alloc((size_t)(N + 1) * NCLS * 2); // +1 dummy zero row
    int* rank            = (int*)alloc((size_t)E * 4);

    const int nbE = (E + 255) / 256;
    const int nbN = (N + 255) / 256;
    const int nbScan = (N + 2047) / 2048;
    const int PB = (HID * IN_F + NCLS * HID) / 256;   // 272 prep blocks (W1T + W2T)
    const int NBG = (N + 63) / 64;                    // gemm tiles; scatter chunks = same count

    hipMemsetAsync(deg, 0, (size_t)N * 4, stream);
    k_histprep<<<PB + nbE, 256, 0, stream>>>(e_dst, deg, rank, E, W1, W1T, W2, W2T, PB);
    k_scan1<<<nbScan, 256, 0, stream>>>(deg, rs, bsum, N);
    k_scan3<<<nbN, 256, 0, stream>>>(rs, bsum, deg, csr, dinv, (unsigned*)hs, (unsigned*)h2s, N, nbScan);

    k_fused<<<2 * NBG, 256, 0, stream>>>(x, W1T, dinv, hs, N, e_src, e_dst, rank, rs, csr, E);

    k_agg1mm<<<(N + 15) / 16, 256, 0, stream>>>(hs, csr, rs, deg, dinv, b1, W2T, h2s, N);
    k_agg2<<<(N + 15) / 16, 256, 0, stream>>>(h2s, csr, rs, deg, dinv, b2, out, N);
}